// Round 10
// baseline (199.800 us; speedup 1.0000x reference)
//
#include <hip/hip_runtime.h>
#include <cstdint>
#include <cstddef>

// Problem constants
#define Bb 2
#define Nn 2048
#define DIMM 1024
#define Hh 16
#define DHh 64
#define BH (Bb*Hh)        // 32
#define MROWS (Bb*Nn)     // 4096

typedef __bf16 bf16x8 __attribute__((ext_vector_type(8)));
typedef float f32x4 __attribute__((ext_vector_type(4)));
typedef short s16x4 __attribute__((ext_vector_type(4)));

__device__ __forceinline__ unsigned short f2bf(float f) {
  unsigned u = __float_as_uint(f);
  u += 0x7FFFu + ((u >> 16) & 1u);       // RNE
  return (unsigned short)(u >> 16);
}
__device__ __forceinline__ unsigned short f2bf_fast(float f) {
  return (unsigned short)((__float_as_uint(f) + 0x8000u) >> 16);
}
__device__ __forceinline__ float bf2f(unsigned short s) {
  return __uint_as_float(((unsigned)s) << 16);
}

// async global->LDS, 16B per lane; LDS dest must be wave-uniform base + lane*16
#define GLDS16(g, l) __builtin_amdgcn_global_load_lds( \
    (const __attribute__((address_space(1))) void*)(g), \
    (__attribute__((address_space(3))) void*)(l), 16, 0, 0)

// ---------------------------------------------------------------------------
// Fused prep: grid-partitioned single kernel.
//   [0,4096):       LayerNorm row -> y bf16
//   [4096,7168):    transpose+convert c_attn_w [1024][3072] -> wqkv [3072][1024]
//   [7168,8192):    convert c_proj_w -> wpbf
//   [8192,9216):    convert to_out_w -> wout
//   [9216,9472):    bias_comb bc[n] = sum_c c_proj_b[c] * to_out_w[n][c]
__global__ __launch_bounds__(256) void prep_kernel(
    const float* __restrict__ x, const float* __restrict__ g,
    const float* __restrict__ b,
    const float* __restrict__ c_attn_w, const float* __restrict__ c_proj_w,
    const float* __restrict__ to_out_w, const float* __restrict__ c_proj_b,
    unsigned short* __restrict__ y,
    unsigned short* __restrict__ wqkv, unsigned short* __restrict__ wpbf,
    unsigned short* __restrict__ wout, float* __restrict__ bc) {
  int bid = blockIdx.x;
  int t = threadIdx.x;
  if (bid < 4096) {
    // LayerNorm, one block per row
    int row = bid;
    const float4* xr = (const float4*)(x + (size_t)row * DIMM);
    float4 v = xr[t];
    float s  = v.x + v.y + v.z + v.w;
    float ss = v.x*v.x + v.y*v.y + v.z*v.z + v.w*v.w;
    #pragma unroll
    for (int o = 1; o < 64; o <<= 1) { s += __shfl_xor(s, o); ss += __shfl_xor(ss, o); }
    __shared__ float red[8];
    int wv = t >> 6;
    if ((t & 63) == 0) { red[wv] = s; red[wv + 4] = ss; }
    __syncthreads();
    s  = red[0] + red[1] + red[2] + red[3];
    ss = red[4] + red[5] + red[6] + red[7];
    float mu  = s * (1.0f / DIMM);
    float var = ss * (1.0f / DIMM) - mu * mu;
    float rs  = rsqrtf(var + 1e-5f);
    float4 gv = ((const float4*)g)[t];
    float4 bv = ((const float4*)b)[t];
    ushort4 o4;
    o4.x = f2bf((v.x - mu) * rs * gv.x + bv.x);
    o4.y = f2bf((v.y - mu) * rs * gv.y + bv.y);
    o4.z = f2bf((v.z - mu) * rs * gv.z + bv.z);
    o4.w = f2bf((v.w - mu) * rs * gv.w + bv.w);
    ((ushort4*)y)[(size_t)row * 256 + t] = o4;
  } else if (bid < 7168) {
    // transpose tile 32x32, c_attn_w R=1024, C=3072
    __shared__ float tile[32][33];
    int bb = bid - 4096;
    int bx = bb % 96, by = bb / 96;
    int tx = t & 31, ty = t >> 5;   // 32 x 8
    int x2 = bx * 32 + tx;
    int y0 = by * 32;
    #pragma unroll
    for (int j = 0; j < 32; j += 8)
      tile[ty + j][tx] = c_attn_w[(size_t)(y0 + ty + j) * 3072 + x2];
    __syncthreads();
    int ox  = by * 32 + tx;
    int oy0 = bx * 32;
    #pragma unroll
    for (int j = 0; j < 32; j += 8)
      wqkv[(size_t)(oy0 + ty + j) * 1024 + ox] = f2bf(tile[tx][ty + j]);
  } else if (bid < 9216) {
    bool iswp = bid < 8192;
    int bb = bid - (iswp ? 7168 : 8192);
    const float* in = iswp ? c_proj_w : to_out_w;
    unsigned short* out = iswp ? wpbf : wout;
    int i = (bb * 256 + t) * 4;
    float4 v = *(const float4*)(in + i);
    ushort4 o;
    o.x = f2bf(v.x); o.y = f2bf(v.y); o.z = f2bf(v.z); o.w = f2bf(v.w);
    *(ushort4*)(out + i) = o;
  } else {
    int n = (bid - 9216) * 4 + (t >> 6);
    int lane = t & 63;
    const float4* w = (const float4*)(to_out_w + (size_t)n * DIMM);
    const float4* b4 = (const float4*)c_proj_b;
    float s = 0.0f;
    #pragma unroll
    for (int k = 0; k < 4; k++) {
      float4 wv = w[lane + k * 64], bv = b4[lane + k * 64];
      s += wv.x * bv.x + wv.y * bv.y + wv.z * bv.z + wv.w * bv.w;
    }
    #pragma unroll
    for (int o = 1; o < 64; o <<= 1) s += __shfl_xor(s, o);
    if (lane == 0) bc[n] = s;
  }
}

// ---------------------------------------------------------------------------
// NT GEMM body: C[M,N] = A[M,K] * Bt[N,K]^T (+bias). 128x128 tile, BK=64,
// 8 waves (512 threads): 2 blocks/CU x 8 waves = 16 waves/CU AND the in-block
// lead-2 counted-vmcnt pipeline. Wave split 4M x 2N: wm=(wv>>1)*32,
// wn=(wv&1)*64 (full 64-wide head slice per wave keeps q/k L2-norm wave-local).
//
// Pipeline per K-tile t (XOR-swizzled LDS, conflict-free; stage = 4 GLDS16):
//   s_waitcnt vmcnt(4)  <- tile t landed; tile t+1's 4 loads stay in flight
//   s_barrier; ds_read + MFMA (setprio around cluster); s_barrier
//   stage tile t+2 -> buf(t&1)   (WAR-safe: reads of buf(t&1) retired)
// vmcnt(0) only at the last tile.
//
// EPI 0: qkv epilogue: q/k scatter [B,H,N,DH] with fused L2-norm; q scaled by
//        8*log2(e) = 11.5415603 (base-2 softmax in attn).
// EPI 2: fp32 out [M,N] + bias
// EPI 3: bf16 out [M,N], no bias
template <int EPI>
__device__ __forceinline__ void gemm_body(
    const unsigned short* __restrict__ A, const unsigned short* __restrict__ Bt,
    const float* __restrict__ bias,
    unsigned short* __restrict__ obf, float* __restrict__ of32,
    unsigned short* __restrict__ q_std, unsigned short* __restrict__ k_std,
    unsigned short* __restrict__ vt_out,
    int M, int N, int K, int bn, int bm,
    unsigned short* smem) {
  int t = threadIdx.x;                   // 0..511
  int lane = t & 63, wv = t >> 6;        // 8 waves
  int wm = (wv >> 1) * 32, wn = (wv & 1) * 64;
  int l16 = lane & 15, quad = lane >> 4;

  const unsigned short* Ab = A + (size_t)(bm * 128) * K;
  const unsigned short* Bb2 = Bt + (size_t)(bn * 128) * K;
  int srow = t >> 3;                     // 0..63
  int gch = (t & 7) ^ (srow & 7);        // swizzled global chunk for this lane

  f32x4 acc[2][4] = {};
  const int KT = K >> 6;                 // 16 for all call sites here

  // stage K-tile kt_ (A 128x64 + B 128x64) into buffer b_ : 4 GLDS16/thread
  auto stage = [&](int kt_, int b_) {
    unsigned short* dA = smem + b_ * 16384;
    unsigned short* dB = dA + 8192;
    const unsigned short* gA = Ab  + (size_t)srow * K + kt_ * 64 + gch * 8;
    const unsigned short* gB = Bb2 + (size_t)srow * K + kt_ * 64 + gch * 8;
    #pragma unroll
    for (int i = 0; i < 2; i++) {
      GLDS16(gA + (size_t)(64 * i) * K, dA + (size_t)(t + 512 * i) * 8);
      GLDS16(gB + (size_t)(64 * i) * K, dB + (size_t)(t + 512 * i) * 8);
    }
  };

  // prologue: two tiles in flight
  stage(0, 0);
  if (KT > 1) stage(1, 1);

  for (int kt2 = 0; kt2 < KT; ++kt2) {
    if (kt2 < KT - 1) asm volatile("s_waitcnt vmcnt(4)" ::: "memory");
    else              asm volatile("s_waitcnt vmcnt(0)" ::: "memory");
    __builtin_amdgcn_s_barrier();
    __builtin_amdgcn_sched_barrier(0);
    const unsigned short* sA = smem + (kt2 & 1) * 16384;
    const unsigned short* sB = sA + 8192;
    #pragma unroll
    for (int kk = 0; kk < 2; kk++) {
      int slot = (kk * 4 + quad) ^ (l16 & 7);
      bf16x8 af[2], bfr[4];
      #pragma unroll
      for (int i = 0; i < 2; i++)
        af[i] = *(const bf16x8*)(sA + (size_t)(wm + i * 16 + l16) * 64 + slot * 8);
      #pragma unroll
      for (int j = 0; j < 4; j++)
        bfr[j] = *(const bf16x8*)(sB + (size_t)(wn + j * 16 + l16) * 64 + slot * 8);
      __builtin_amdgcn_s_setprio(1);
      #pragma unroll
      for (int i = 0; i < 2; i++)
        #pragma unroll
        for (int j = 0; j < 4; j++)
          acc[i][j] = __builtin_amdgcn_mfma_f32_16x16x32_bf16(af[i], bfr[j], acc[i][j], 0, 0, 0);
      __builtin_amdgcn_s_setprio(0);
    }
    __builtin_amdgcn_sched_barrier(0);
    __builtin_amdgcn_s_barrier();
    __builtin_amdgcn_sched_barrier(0);
    if (kt2 + 2 < KT) stage(kt2 + 2, kt2 & 1);
  }

  // epilogue: D row = quad*4+reg, col = l16
  float bvals[4];
  #pragma unroll
  for (int j = 0; j < 4; j++)
    bvals[j] = (EPI == 3) ? 0.0f : bias[bn * 128 + wn + j * 16 + l16];

  if (EPI == 0) {
    int which = bn >> 3;                 // 0=q 1=k 2=v  (block-uniform)
    if (which < 2) {
      #pragma unroll
      for (int i = 0; i < 2; i++) {
        #pragma unroll
        for (int r = 0; r < 4; r++) {
          int m = bm * 128 + wm + i * 16 + quad * 4 + r;
          float vals[4];
          float ss = 0.0f;
          #pragma unroll
          for (int j = 0; j < 4; j++) {
            vals[j] = acc[i][j][r] + bvals[j];
            ss += vals[j] * vals[j];
          }
          ss += __shfl_xor(ss, 1); ss += __shfl_xor(ss, 2);
          ss += __shfl_xor(ss, 4); ss += __shfl_xor(ss, 8);
          // q scaled by 8*log2(e) so attention can use exp2 directly
          float scale = ((which == 0) ? 11.5415603f : 1.0f) / fmaxf(sqrtf(ss), 1e-12f);
          int bi = m >> 11, ns = m & 2047;
          unsigned short* dst = (which == 0) ? q_std : k_std;
          #pragma unroll
          for (int j = 0; j < 4; j++) {
            int n = bn * 128 + wn + j * 16 + l16;
            int nn2 = n & 1023;
            int h = nn2 >> 6, d = nn2 & 63;
            dst[((size_t)((bi * Hh + h) * Nn + ns)) * DHh + d] = f2bf(vals[j] * scale);
          }
        }
      }
    } else {
      // v-block: transpose tile through LDS (32 KB, reuses buf0), write
      // vt[bh][d][n_seq] with coalesced-ish 8B stores. Swizzle at 4-short
      // granularity: chunk c (m_local>>2), c' = c ^ (n_local & 31).
      __syncthreads();                   // all waves done with LDS reads
      #pragma unroll
      for (int i = 0; i < 2; i++) {
        int mchunk = (wm + i * 16) / 4 + quad;   // 0..31
        #pragma unroll
        for (int j = 0; j < 4; j++) {
          int n_local = wn + j * 16 + l16;
          int sw = mchunk ^ (n_local & 31);
          ushort4 pack;
          pack.x = f2bf(acc[i][j][0] + bvals[j]);
          pack.y = f2bf(acc[i][j][1] + bvals[j]);
          pack.z = f2bf(acc[i][j][2] + bvals[j]);
          pack.w = f2bf(acc[i][j][3] + bvals[j]);
          *(ushort4*)(smem + (size_t)n_local * 128 + sw * 4) = pack;
        }
      }
      __syncthreads();
      // thread t: row d = t>>2 (n_local), m-quarter = t&3 (32 m-values, 8 chunks)
      int drow = t >> 2, mq = t & 3;
      int h = (bn - 16) * 2 + (drow >> 6);
      int d = drow & 63;
      int bi = bm >> 4;
      int ns0 = (bm * 128) & 2047;
      unsigned short* dst = vt_out + ((size_t)(bi * Hh + h) * DHh + d) * Nn + ns0 + mq * 32;
      #pragma unroll
      for (int cc = 0; cc < 8; cc++) {
        int c0 = mq * 8 + cc;
        int s0 = c0 ^ (drow & 31);
        *(ushort4*)(dst + cc * 4) = *(const ushort4*)(smem + (size_t)drow * 128 + s0 * 4);
      }
    }
  } else {
    #pragma unroll
    for (int i = 0; i < 2; i++) {
      #pragma unroll
      for (int j = 0; j < 4; j++) {
        int n = bn * 128 + wn + j * 16 + l16;
        #pragma unroll
        for (int r = 0; r < 4; r++) {
          int m = bm * 128 + wm + i * 16 + quad * 4 + r;
          float val = acc[i][j][r] + bvals[j];
          if (EPI == 2) of32[(size_t)m * N + n] = val;
          else          obf[(size_t)m * N + n] = f2bf(val);
        }
      }
    }
  }
}

// Fused launch: qkv GEMM (bn<24, grid 24x32) + wcomb GEMM (bn in {24,25},
// remapped to the 8x8 tile grid of wcomb[n][j] = sum_c Wo[n][c]*Wp[j][c]).
__global__ __launch_bounds__(512, 4) void gemm_qkv_wcomb(
    const unsigned short* __restrict__ y, const unsigned short* __restrict__ wqkv,
    const float* __restrict__ c_attn_b,
    unsigned short* __restrict__ q_std, unsigned short* __restrict__ k_std,
    unsigned short* __restrict__ vt_out,
    const unsigned short* __restrict__ wout, const unsigned short* __restrict__ wpbf,
    unsigned short* __restrict__ wcomb) {
  __shared__ unsigned short smem[32768];   // 64 KB: 2 x (A 16KB + B 16KB)
  int bn = blockIdx.x, bm = blockIdx.y;
  if (bn < 24) {
    gemm_body<0>(y, wqkv, c_attn_b, nullptr, nullptr, q_std, k_std, vt_out,
                 MROWS, 3 * DIMM, DIMM, bn, bm, smem);
  } else {
    int idx = (bn - 24) * 32 + bm;       // 0..63
    gemm_body<3>(wout, wpbf, nullptr, wcomb, nullptr, nullptr, nullptr, nullptr,
                 DIMM, DIMM, DIMM, idx & 7, idx >> 3, smem);
  }
}

// Standalone final GEMM (fp32 out + bias)
__global__ __launch_bounds__(512, 4) void gemm_final(
    const unsigned short* __restrict__ A, const unsigned short* __restrict__ Bt,
    const float* __restrict__ bias, float* __restrict__ of32) {
  __shared__ unsigned short smem[32768];   // 64 KB: 2 x (A 16KB + B 16KB)
  gemm_body<2>(A, Bt, bias, nullptr, of32, nullptr, nullptr, nullptr,
               MROWS, DIMM, DIMM, blockIdx.x, blockIdx.y, smem);
}

// ---------------------------------------------------------------------------
// Causal cosine-sim attention — R10: KVBLK=128, single-buffered, PASS-
// INTERLEAVED (fixes R9's register spill).
// R9 post-mortem: KVBLK=128 halved barrier intervals as designed, but holding
// pf[8][2] across both QK passes spilled (~15 MB scratch: WRITE 8.2->23.5 MB,
// FETCH 12.3->19.9 MB, ~5 µs). R10: per pass p in {0,1}:
//   QK(jt 0-3 of this pass) -> exp -> PV(jt 0-3 of this pass)
// so only pf[4][2] is ever live (R4-proven register level). Keeps the halved
// barrier count. Per-pass wave-uniform skip when fully masked.
// Schedule per 128-j tile: barrier -> stage (8 GLDS16) -> vmcnt(0) ->
// barrier -> compute. Exposed stage latency hidden by the co-resident block
// (m114). den scalar+shfl; base-2 exp (q pre-scaled 8*log2e).
// Masking: half0 zeroes j >= jlim=(qb+1)*64 (128-tile straddle when qb+1
// odd); half1's top is causal-masked.
__global__ __launch_bounds__(512, 4) void attn_kernel(
    const unsigned short* __restrict__ qn, const unsigned short* __restrict__ kn,
    const unsigned short* __restrict__ vt, unsigned short* __restrict__ o_flat) {
  __shared__ float smemf[16384];   // 64 KB: 2 halves x (K 16KB + V 16KB); merge reuses front
  int t = threadIdx.x, lane = t & 63, wv = t >> 6;
  int half = wv >> 2, strip = wv & 3;
  int l16 = lane & 15, quad = lane >> 4;
  int id = blockIdx.x;
  int qb = (id < 256) ? (15 - (id >> 5)) : ((id - 256) >> 5);  // pair heavy+light
  int bh = id & 31;
  int m0 = qb * 128 + strip * 32;               // wave's first q row (seq index)
  const unsigned short* qbase = qn + (size_t)bh * Nn * DHh;
  const unsigned short* kbase = kn + (size_t)bh * Nn * DHh;
  const unsigned short* vbase = vt + (size_t)bh * DHh * Nn;

  // Q fragments (q pre-scaled by 8*log2e); lane layout = MFMA B-operand
  bf16x8 aq[2][2];
  #pragma unroll
  for (int i2 = 0; i2 < 2; i2++)
    #pragma unroll
    for (int kk = 0; kk < 2; kk++)
      aq[i2][kk] = *(const bf16x8*)(qbase + (size_t)(m0 + i2 * 16 + l16) * DHh + kk * 32 + quad * 8);

  f32x4 accOT[4][2] = {};       // [dt][i2]: O^T, row=d=quad*4+r, col=m=l16
  float den[2] = {};            // per-lane partial (quad-partial), m = i2*16+l16

  int tl = t & 255;                      // thread-in-halfgroup
  int nh2 = (qb + 2) >> 1;               // 128-wide tiles per half
  int jstart = half * ((qb + 1) * 64);   // half0: 0 ; half1: (qb+1)*64
  int jlim = half ? Nn : (qb + 1) * 64;  // half0 must not overlap half1's range

  unsigned short* K_ = (unsigned short*)((char*)smemf + half * 32768);
  unsigned short* V_ = K_ + 8192;        // 16 KB each

  // staging: LDS is linear in (tl + 256*i); swizzle lives in the SOURCE addr.
  // K slot = row*8 + cs (row = (tl>>3)+32i, cs = tl&7), src chunk = cs^(row&7)
  // V slot = row*16 + cs (row = (tl>>4)+16i, cs = tl&15), src chunk = cs^(row&15)
  int krow = tl >> 3;                    // 0..31
  int kg   = (tl & 7) ^ (krow & 7);
  int vrow = tl >> 4;                    // 0..15
  int vg   = (tl & 15) ^ vrow;

  auto stageT = [&](int kt_) {
    int j0 = jstart + kt_ * 128;
    #pragma unroll
    for (int i = 0; i < 4; i++)
      GLDS16(kbase + (size_t)(j0 + krow + 32 * i) * DHh + kg * 8, K_ + (size_t)(tl + 256 * i) * 8);
    #pragma unroll
    for (int i = 0; i < 4; i++)
      GLDS16(vbase + (size_t)(vrow + 16 * i) * Nn + j0 + vg * 8, V_ + (size_t)(tl + 256 * i) * 8);
  };

  for (int kt = 0; kt < nh2; kt++) {
    int j0 = jstart + kt * 128;
    __builtin_amdgcn_s_barrier();        // prev compute done by all -> buffer free
    stageT(kt);
    asm volatile("s_waitcnt vmcnt(0)" ::: "memory");
    __builtin_amdgcn_s_barrier();        // all threads' stores visible
    __builtin_amdgcn_sched_barrier(0);

    if (j0 <= m0 + 31) {                 // not fully masked (wave-uniform)
      #pragma unroll
      for (int pass = 0; pass < 2; pass++) {
        int jp = j0 + pass * 64;
        if (jp > m0 + 31) break;         // pass fully masked (wave-uniform)

        // S^T = K·Q^T for j-rows [jp, jp+64)
        f32x4 sc[4][2] = {};
        #pragma unroll
        for (int kk = 0; kk < 2; kk++) {
          int slot = (kk * 4 + quad) ^ (l16 & 7);
          #pragma unroll
          for (int jt = 0; jt < 4; jt++) {
            int row = (pass * 4 + jt) * 16 + l16;
            bf16x8 ak = *(const bf16x8*)(K_ + (size_t)row * 64 + slot * 8);
            #pragma unroll
            for (int i2 = 0; i2 < 2; i2++)
              sc[jt][i2] = __builtin_amdgcn_mfma_f32_16x16x32_bf16(ak, aq[i2][kk], sc[jt][i2], 0, 0, 0);
          }
        }

        // p = 2^(sc - 8*log2e); mask j>m (causal) and j>=jlim (half overlap)
        bool full = (jp + 63 <= m0) && (jp + 64 <= jlim);
        s16x4 pf[4][2];
        #pragma unroll
        for (int jt = 0; jt < 4; jt++) {
          #pragma unroll
          for (int i2 = 0; i2 < 2; i2++) {
            int m = m0 + i2 * 16 + l16;
            #pragma unroll
            for (int r = 0; r < 4; r++) {
              int j = jp + jt * 16 + quad * 4 + r;
              float e = sc[jt][i2][r] - 11.5415603f;
              float p;
              asm("v_exp_f32 %0, %1" : "=v"(p) : "v"(e));
              if (!full && (j > m || j >= jlim)) p = 0.0f;
              den[i2] += p;
              pf[jt][i2][r] = (short)f2bf_fast(p);
            }
          }
        }

        // O^T += V^T · P^T for this pass's 4 jt
        #pragma unroll
        for (int jt = 0; jt < 4; jt++) {
          int cj = 2 * (pass * 4 + jt) + (quad >> 1);  // 16B chunk in 128-j row
          #pragma unroll
          for (int dt = 0; dt < 4; dt++) {
            int row = dt * 16 + l16;
            int cs = cj ^ l16;           // row&15 == l16
            s16x4 av = *(const s16x4*)(V_ + (size_t)row * 128 + cs * 8 + (quad & 1) * 4);
            #pragma unroll
            for (int i2 = 0; i2 < 2; i2++)
              accOT[dt][i2] = __builtin_amdgcn_mfma_f32_16x16x16bf16_1k(av, pf[jt][i2], accOT[dt][i2], 0, 0, 0);
          }
        }
      }
    }
  }

  // intra-wave den reduction across quads (j-direction lives on lane>>4)
  #pragma unroll
  for (int i2 = 0; i2 < 2; i2++) {
    float d = den[i2];
    d += __shfl_xor(d, 16); d += __shfl_xor(d, 32);
    den[i2] = d;
  }

  // merge halves through LDS (reuse tile buffers; all loop reads done)
  __syncthreads();
  float* scr = smemf + strip * 2176;     // 2048 acc + 128 den per strip
  if (half == 1) {
    #pragma unroll
    for (int dt = 0; dt < 4; dt++)
      #pragma unroll
      for (int i2 = 0; i2 < 2; i2++)
        *(f32x4*)(scr + ((size_t)(dt * 2 + i2) * 64 + lane) * 4) = accOT[dt][i2];
    scr[2048 + lane] = den[0];
    scr[2048 + 64 + lane] = den[1];
  }
  __syncthreads();
  if (half == 0) {
    float dinv[2];
    dinv[0] = 1.0f / (den[0] + scr[2048 + lane]);
    dinv[1] = 1.0f / (den[1] + scr[2048 + 64 + lane]);
    int bi = bh >> 4, h = bh & 15;
    #pragma unroll
    for (int i2 = 0; i2 < 2; i2++) {
      #pragma unroll
      for (int dt = 0; dt < 4; dt++) {
        f32x4 o = accOT[dt][i2] + *(const f32x4*)(scr + ((size_t)(dt * 2 + i2) * 64 + lane) * 4);
        ushort4 o4;
        o4.x = f2bf(o[0] * dinv[i2]);
        o4.y = f2bf(o[1] * dinv[i2]);
        o4.z = f2bf(o[2] * dinv[i2]);
        o4.w = f2bf(o[3] * dinv[i2]);
        int ns = m0 + i2 * 16 + l16;
        int d0 = dt * 16 + quad * 4;
        *(ushort4*)(o_flat + ((size_t)(bi * Nn + ns)) * DIMM + h * DHh + d0) = o4;
      }
    }
  }
}

// ---------------------------------------------------------------------------
extern "C" void kernel_launch(void* const* d_in, const int* in_sizes, int n_in,
                              void* d_out, int out_size, void* d_ws, size_t ws_size,
                              hipStream_t stream) {
  const float* x        = (const float*)d_in[0];
  const float* g        = (const float*)d_in[1];
  const float* b        = (const float*)d_in[2];
  const float* c_attn_w = (const float*)d_in[3];
  const float* c_attn_b = (const float*)d_in[4];
  const float* c_proj_w = (const float*)d_in[5];
  const float* c_proj_b = (const float*)d_in[6];
  const float* to_out_w = (const float*)d_in[7];
  float* out = (float*)d_out;

  char* p = (char*)d_ws;
  unsigned short* y     = (unsigned short*)(p + ((size_t)0  << 20)); // 8 MB (also o_flat)
  unsigned short* qbuf  = (unsigned short*)(p + ((size_t)8  << 20)); // 8 MB
  unsigned short* kbuf  = (unsigned short*)(p + ((size_t)16 << 20)); // 8 MB
  unsigned short* vtb   = (unsigned short*)(p + ((size_t)24 << 20)); // 8 MB (V^T, written by qkv epilogue)
  unsigned short* wpbf  = (unsigned short*)(p + ((size_t)32 << 20)); // 2 MB
  unsigned short* wout  = (unsigned short*)(p + ((size_t)34 << 20)); // 2 MB
  unsigned short* wqkv  = (unsigned short*)(p + ((size_t)40 << 20)); // 6 MB
  unsigned short* wcomb = (unsigned short*)(p + ((size_t)46 << 20)); // 2 MB
  float*          bc    = (float*)        (p + ((size_t)48 << 20)); // 4 KB

  // 1. fused prep: LayerNorm -> y, transpose c_attn_w, convert wp/wout, bias
  prep_kernel<<<9472, 256, 0, stream>>>(x, g, b, c_attn_w, c_proj_w, to_out_w,
                                        c_proj_b, y, wqkv, wpbf, wout, bc);
  // 2. qkv GEMM (+fused l2norm, +fused V-transpose) with wcomb GEMM riding
  gemm_qkv_wcomb<<<dim3(26, MROWS / 128), 512, 0, stream>>>(
      y, wqkv, c_attn_b, qbuf, kbuf, vtb, wout, wpbf, wcomb);
  // 3. attention -> o_flat (reuses y)
  attn_kernel<<<512, 512, 0, stream>>>(qbuf, kbuf, vtb, y);
  // 4. fused (c_proj ∘ to_out): out = o_flat @ wcomb^T + bc  (fp32)
  gemm_final<<<dim3(DIMM / 128, MROWS / 128), 512, 0, stream>>>(y, wcomb, bc, out);
}

// Round 11
// 185.064 us; speedup vs baseline: 1.0796x; 1.0796x over previous
//
#include <hip/hip_runtime.h>
#include <cstdint>
#include <cstddef>

// Problem constants
#define Bb 2
#define Nn 2048
#define DIMM 1024
#define Hh 16
#define DHh 64
#define BH (Bb*Hh)        // 32
#define MROWS (Bb*Nn)     // 4096

typedef __bf16 bf16x8 __attribute__((ext_vector_type(8)));
typedef float f32x4 __attribute__((ext_vector_type(4)));
typedef short s16x4 __attribute__((ext_vector_type(4)));

__device__ __forceinline__ unsigned short f2bf(float f) {
  unsigned u = __float_as_uint(f);
  u += 0x7FFFu + ((u >> 16) & 1u);       // RNE
  return (unsigned short)(u >> 16);
}
__device__ __forceinline__ unsigned short f2bf_fast(float f) {
  return (unsigned short)((__float_as_uint(f) + 0x8000u) >> 16);
}
__device__ __forceinline__ float bf2f(unsigned short s) {
  return __uint_as_float(((unsigned)s) << 16);
}

// async global->LDS, 16B per lane; LDS dest must be wave-uniform base + lane*16
#define GLDS16(g, l) __builtin_amdgcn_global_load_lds( \
    (const __attribute__((address_space(1))) void*)(g), \
    (__attribute__((address_space(3))) void*)(l), 16, 0, 0)

// ---------------------------------------------------------------------------
// Fused prep: grid-partitioned single kernel.
//   [0,4096):       LayerNorm row -> y bf16
//   [4096,7168):    transpose+convert c_attn_w [1024][3072] -> wqkv [3072][1024]
//   [7168,8192):    convert c_proj_w -> wpbf
//   [8192,9216):    convert to_out_w -> wout
//   [9216,9472):    bias_comb bc[n] = sum_c c_proj_b[c] * to_out_w[n][c]
__global__ __launch_bounds__(256) void prep_kernel(
    const float* __restrict__ x, const float* __restrict__ g,
    const float* __restrict__ b,
    const float* __restrict__ c_attn_w, const float* __restrict__ c_proj_w,
    const float* __restrict__ to_out_w, const float* __restrict__ c_proj_b,
    unsigned short* __restrict__ y,
    unsigned short* __restrict__ wqkv, unsigned short* __restrict__ wpbf,
    unsigned short* __restrict__ wout, float* __restrict__ bc) {
  int bid = blockIdx.x;
  int t = threadIdx.x;
  if (bid < 4096) {
    // LayerNorm, one block per row
    int row = bid;
    const float4* xr = (const float4*)(x + (size_t)row * DIMM);
    float4 v = xr[t];
    float s  = v.x + v.y + v.z + v.w;
    float ss = v.x*v.x + v.y*v.y + v.z*v.z + v.w*v.w;
    #pragma unroll
    for (int o = 1; o < 64; o <<= 1) { s += __shfl_xor(s, o); ss += __shfl_xor(ss, o); }
    __shared__ float red[8];
    int wv = t >> 6;
    if ((t & 63) == 0) { red[wv] = s; red[wv + 4] = ss; }
    __syncthreads();
    s  = red[0] + red[1] + red[2] + red[3];
    ss = red[4] + red[5] + red[6] + red[7];
    float mu  = s * (1.0f / DIMM);
    float var = ss * (1.0f / DIMM) - mu * mu;
    float rs  = rsqrtf(var + 1e-5f);
    float4 gv = ((const float4*)g)[t];
    float4 bv = ((const float4*)b)[t];
    ushort4 o4;
    o4.x = f2bf((v.x - mu) * rs * gv.x + bv.x);
    o4.y = f2bf((v.y - mu) * rs * gv.y + bv.y);
    o4.z = f2bf((v.z - mu) * rs * gv.z + bv.z);
    o4.w = f2bf((v.w - mu) * rs * gv.w + bv.w);
    ((ushort4*)y)[(size_t)row * 256 + t] = o4;
  } else if (bid < 7168) {
    // transpose tile 32x32, c_attn_w R=1024, C=3072
    __shared__ float tile[32][33];
    int bb = bid - 4096;
    int bx = bb % 96, by = bb / 96;
    int tx = t & 31, ty = t >> 5;   // 32 x 8
    int x2 = bx * 32 + tx;
    int y0 = by * 32;
    #pragma unroll
    for (int j = 0; j < 32; j += 8)
      tile[ty + j][tx] = c_attn_w[(size_t)(y0 + ty + j) * 3072 + x2];
    __syncthreads();
    int ox  = by * 32 + tx;
    int oy0 = bx * 32;
    #pragma unroll
    for (int j = 0; j < 32; j += 8)
      wqkv[(size_t)(oy0 + ty + j) * 1024 + ox] = f2bf(tile[tx][ty + j]);
  } else if (bid < 9216) {
    bool iswp = bid < 8192;
    int bb = bid - (iswp ? 7168 : 8192);
    const float* in = iswp ? c_proj_w : to_out_w;
    unsigned short* out = iswp ? wpbf : wout;
    int i = (bb * 256 + t) * 4;
    float4 v = *(const float4*)(in + i);
    ushort4 o;
    o.x = f2bf(v.x); o.y = f2bf(v.y); o.z = f2bf(v.z); o.w = f2bf(v.w);
    *(ushort4*)(out + i) = o;
  } else {
    int n = (bid - 9216) * 4 + (t >> 6);
    int lane = t & 63;
    const float4* w = (const float4*)(to_out_w + (size_t)n * DIMM);
    const float4* b4 = (const float4*)c_proj_b;
    float s = 0.0f;
    #pragma unroll
    for (int k = 0; k < 4; k++) {
      float4 wv = w[lane + k * 64], bv = b4[lane + k * 64];
      s += wv.x * bv.x + wv.y * bv.y + wv.z * bv.z + wv.w * bv.w;
    }
    #pragma unroll
    for (int o = 1; o < 64; o <<= 1) s += __shfl_xor(s, o);
    if (lane == 0) bc[n] = s;
  }
}

// ---------------------------------------------------------------------------
// NT GEMM body: C[M,N] = A[M,K] * Bt[N,K]^T (+bias). 128x128 tile, BK=64,
// 8 waves (512 threads): 2 blocks/CU x 8 waves = 16 waves/CU AND the in-block
// lead-2 counted-vmcnt pipeline. Wave split 4M x 2N: wm=(wv>>1)*32,
// wn=(wv&1)*64 (full 64-wide head slice per wave keeps q/k L2-norm wave-local).
//
// R11 schedule per K-tile t (XOR-swizzled LDS, conflict-free; stage=4 GLDS16):
//   s_waitcnt vmcnt(4)  <- tile t landed; tile t+1's 4 loads stay in flight
//   s_barrier
//   ds_read all 12 fragments of tile t
//   lgkmcnt(0); s_barrier   <- all waves' reads of buf(t&1) retired (WAR-safe)
//   stage tile t+2 -> buf(t&1)   <- issued BEFORE the MFMA cluster: loads get
//                                   the whole cluster (~250cy) extra in flight
//   setprio(1); 16 MFMA; setprio(0)
// vmcnt(0) only at the last tile. Still 2 barriers/iter; staging no longer
// serial-after-compute (R10 had it dead-after-barrier).
//
// EPI 0: qkv epilogue: q/k scatter [B,H,N,DH] with fused L2-norm; q scaled by
//        8*log2(e) = 11.5415603 (base-2 softmax in attn).
// EPI 2: fp32 out [M,N] + bias
// EPI 3: bf16 out [M,N], no bias
template <int EPI>
__device__ __forceinline__ void gemm_body(
    const unsigned short* __restrict__ A, const unsigned short* __restrict__ Bt,
    const float* __restrict__ bias,
    unsigned short* __restrict__ obf, float* __restrict__ of32,
    unsigned short* __restrict__ q_std, unsigned short* __restrict__ k_std,
    unsigned short* __restrict__ vt_out,
    int M, int N, int K, int bn, int bm,
    unsigned short* smem) {
  int t = threadIdx.x;                   // 0..511
  int lane = t & 63, wv = t >> 6;        // 8 waves
  int wm = (wv >> 1) * 32, wn = (wv & 1) * 64;
  int l16 = lane & 15, quad = lane >> 4;

  const unsigned short* Ab = A + (size_t)(bm * 128) * K;
  const unsigned short* Bb2 = Bt + (size_t)(bn * 128) * K;
  int srow = t >> 3;                     // 0..63
  int gch = (t & 7) ^ (srow & 7);        // swizzled global chunk for this lane

  f32x4 acc[2][4] = {};
  const int KT = K >> 6;                 // 16 for all call sites here

  // stage K-tile kt_ (A 128x64 + B 128x64) into buffer b_ : 4 GLDS16/thread
  auto stage = [&](int kt_, int b_) {
    unsigned short* dA = smem + b_ * 16384;
    unsigned short* dB = dA + 8192;
    const unsigned short* gA = Ab  + (size_t)srow * K + kt_ * 64 + gch * 8;
    const unsigned short* gB = Bb2 + (size_t)srow * K + kt_ * 64 + gch * 8;
    #pragma unroll
    for (int i = 0; i < 2; i++) {
      GLDS16(gA + (size_t)(64 * i) * K, dA + (size_t)(t + 512 * i) * 8);
      GLDS16(gB + (size_t)(64 * i) * K, dB + (size_t)(t + 512 * i) * 8);
    }
  };

  // prologue: two tiles in flight
  stage(0, 0);
  if (KT > 1) stage(1, 1);

  for (int kt2 = 0; kt2 < KT; ++kt2) {
    if (kt2 < KT - 1) asm volatile("s_waitcnt vmcnt(4)" ::: "memory");
    else              asm volatile("s_waitcnt vmcnt(0)" ::: "memory");
    __builtin_amdgcn_s_barrier();
    __builtin_amdgcn_sched_barrier(0);
    const unsigned short* sA = smem + (kt2 & 1) * 16384;
    const unsigned short* sB = sA + 8192;
    bf16x8 af[2][2], bfr[2][4];
    #pragma unroll
    for (int kk = 0; kk < 2; kk++) {
      int slot = (kk * 4 + quad) ^ (l16 & 7);
      #pragma unroll
      for (int i = 0; i < 2; i++)
        af[kk][i] = *(const bf16x8*)(sA + (size_t)(wm + i * 16 + l16) * 64 + slot * 8);
      #pragma unroll
      for (int j = 0; j < 4; j++)
        bfr[kk][j] = *(const bf16x8*)(sB + (size_t)(wn + j * 16 + l16) * 64 + slot * 8);
    }
    asm volatile("s_waitcnt lgkmcnt(0)" ::: "memory");
    __builtin_amdgcn_sched_barrier(0);
    __builtin_amdgcn_s_barrier();        // all waves' reads of buf(kt2&1) done
    __builtin_amdgcn_sched_barrier(0);
    if (kt2 + 2 < KT) stage(kt2 + 2, kt2 & 1);   // overlap staging with MFMAs
    __builtin_amdgcn_s_setprio(1);
    #pragma unroll
    for (int kk = 0; kk < 2; kk++)
      #pragma unroll
      for (int i = 0; i < 2; i++)
        #pragma unroll
        for (int j = 0; j < 4; j++)
          acc[i][j] = __builtin_amdgcn_mfma_f32_16x16x32_bf16(af[kk][i], bfr[kk][j], acc[i][j], 0, 0, 0);
    __builtin_amdgcn_s_setprio(0);
  }

  // epilogue: D row = quad*4+reg, col = l16
  float bvals[4];
  #pragma unroll
  for (int j = 0; j < 4; j++)
    bvals[j] = (EPI == 3) ? 0.0f : bias[bn * 128 + wn + j * 16 + l16];

  if (EPI == 0) {
    int which = bn >> 3;                 // 0=q 1=k 2=v  (block-uniform)
    if (which < 2) {
      #pragma unroll
      for (int i = 0; i < 2; i++) {
        #pragma unroll
        for (int r = 0; r < 4; r++) {
          int m = bm * 128 + wm + i * 16 + quad * 4 + r;
          float vals[4];
          float ss = 0.0f;
          #pragma unroll
          for (int j = 0; j < 4; j++) {
            vals[j] = acc[i][j][r] + bvals[j];
            ss += vals[j] * vals[j];
          }
          ss += __shfl_xor(ss, 1); ss += __shfl_xor(ss, 2);
          ss += __shfl_xor(ss, 4); ss += __shfl_xor(ss, 8);
          // q scaled by 8*log2(e) so attention can use exp2 directly
          float scale = ((which == 0) ? 11.5415603f : 1.0f) / fmaxf(sqrtf(ss), 1e-12f);
          int bi = m >> 11, ns = m & 2047;
          unsigned short* dst = (which == 0) ? q_std : k_std;
          #pragma unroll
          for (int j = 0; j < 4; j++) {
            int n = bn * 128 + wn + j * 16 + l16;
            int nn2 = n & 1023;
            int h = nn2 >> 6, d = nn2 & 63;
            dst[((size_t)((bi * Hh + h) * Nn + ns)) * DHh + d] = f2bf(vals[j] * scale);
          }
        }
      }
    } else {
      // v-block: transpose tile through LDS (32 KB, reuses buf0), write
      // vt[bh][d][n_seq] with coalesced-ish 8B stores. Swizzle at 4-short
      // granularity: chunk c (m_local>>2), c' = c ^ (n_local & 31).
      __syncthreads();                   // all waves done with LDS reads
      #pragma unroll
      for (int i = 0; i < 2; i++) {
        int mchunk = (wm + i * 16) / 4 + quad;   // 0..31
        #pragma unroll
        for (int j = 0; j < 4; j++) {
          int n_local = wn + j * 16 + l16;
          int sw = mchunk ^ (n_local & 31);
          ushort4 pack;
          pack.x = f2bf(acc[i][j][0] + bvals[j]);
          pack.y = f2bf(acc[i][j][1] + bvals[j]);
          pack.z = f2bf(acc[i][j][2] + bvals[j]);
          pack.w = f2bf(acc[i][j][3] + bvals[j]);
          *(ushort4*)(smem + (size_t)n_local * 128 + sw * 4) = pack;
        }
      }
      __syncthreads();
      // thread t: row d = t>>2 (n_local), m-quarter = t&3 (32 m-values, 8 chunks)
      int drow = t >> 2, mq = t & 3;
      int h = (bn - 16) * 2 + (drow >> 6);
      int d = drow & 63;
      int bi = bm >> 4;
      int ns0 = (bm * 128) & 2047;
      unsigned short* dst = vt_out + ((size_t)(bi * Hh + h) * DHh + d) * Nn + ns0 + mq * 32;
      #pragma unroll
      for (int cc = 0; cc < 8; cc++) {
        int c0 = mq * 8 + cc;
        int s0 = c0 ^ (drow & 31);
        *(ushort4*)(dst + cc * 4) = *(const ushort4*)(smem + (size_t)drow * 128 + s0 * 4);
      }
    }
  } else {
    #pragma unroll
    for (int i = 0; i < 2; i++) {
      #pragma unroll
      for (int j = 0; j < 4; j++) {
        int n = bn * 128 + wn + j * 16 + l16;
        #pragma unroll
        for (int r = 0; r < 4; r++) {
          int m = bm * 128 + wm + i * 16 + quad * 4 + r;
          float val = acc[i][j][r] + bvals[j];
          if (EPI == 2) of32[(size_t)m * N + n] = val;
          else          obf[(size_t)m * N + n] = f2bf(val);
        }
      }
    }
  }
}

// Fused launch: qkv GEMM (bn<24, grid 24x32) + wcomb GEMM (bn in {24,25},
// remapped to the 8x8 tile grid of wcomb[n][j] = sum_c Wo[n][c]*Wp[j][c]).
__global__ __launch_bounds__(512, 4) void gemm_qkv_wcomb(
    const unsigned short* __restrict__ y, const unsigned short* __restrict__ wqkv,
    const float* __restrict__ c_attn_b,
    unsigned short* __restrict__ q_std, unsigned short* __restrict__ k_std,
    unsigned short* __restrict__ vt_out,
    const unsigned short* __restrict__ wout, const unsigned short* __restrict__ wpbf,
    unsigned short* __restrict__ wcomb) {
  __shared__ unsigned short smem[32768];   // 64 KB: 2 x (A 16KB + B 16KB)
  int bn = blockIdx.x, bm = blockIdx.y;
  if (bn < 24) {
    gemm_body<0>(y, wqkv, c_attn_b, nullptr, nullptr, q_std, k_std, vt_out,
                 MROWS, 3 * DIMM, DIMM, bn, bm, smem);
  } else {
    int idx = (bn - 24) * 32 + bm;       // 0..63
    gemm_body<3>(wout, wpbf, nullptr, wcomb, nullptr, nullptr, nullptr, nullptr,
                 DIMM, DIMM, DIMM, idx & 7, idx >> 3, smem);
  }
}

// Standalone final GEMM (fp32 out + bias)
__global__ __launch_bounds__(512, 4) void gemm_final(
    const unsigned short* __restrict__ A, const unsigned short* __restrict__ Bt,
    const float* __restrict__ bias, float* __restrict__ of32) {
  __shared__ unsigned short smem[32768];   // 64 KB: 2 x (A 16KB + B 16KB)
  gemm_body<2>(A, Bt, bias, nullptr, of32, nullptr, nullptr, nullptr,
               MROWS, DIMM, DIMM, blockIdx.x, blockIdx.y, smem);
}

// ---------------------------------------------------------------------------
// Causal cosine-sim attention — R11: REVERT to the R4 structure (best
// measured: 50.0 µs, WRITE 8.19 MB clean, VGPR 64), keeping only the
// register-neutral base-2 exp (q pre-scaled by 8*log2e in the qkv epilogue).
// R9/R10 lesson: KVBLK=128 variants spill at the (512,4) register budget
// (WRITE 16-24 MB scratch) and lose to R4 despite halved barrier count.
// Structure: 512 blocks x 512 thr, KVBLK=64, split-j halves, lead-2
// counted-vmcnt double-buffer, no setprio in body, scalar den + shfl.
//   S^T = K·Q^T via mfma(A=K, B=Q);  P^T exp'd in-register = B-operand of
//   16x16x16 MFMA;  O^T[d][m] += V^T[d][j]·P^T[j][m]
__global__ __launch_bounds__(512, 4) void attn_kernel(
    const unsigned short* __restrict__ qn, const unsigned short* __restrict__ kn,
    const unsigned short* __restrict__ vt, unsigned short* __restrict__ o_flat) {
  __shared__ float smemf[16384];   // 65536 B: 2 halves x 2 bufs x 16 KB
  int t = threadIdx.x, lane = t & 63, wv = t >> 6;
  int half = wv >> 2, strip = wv & 3;
  int l16 = lane & 15, quad = lane >> 4;
  int id = blockIdx.x;
  int qb = (id < 256) ? (15 - (id >> 5)) : ((id - 256) >> 5);  // pair heavy+light
  int bh = id & 31;
  int m0 = qb * 128 + strip * 32;               // wave's first q row (seq index)
  const unsigned short* qbase = qn + (size_t)bh * Nn * DHh;
  const unsigned short* kbase = kn + (size_t)bh * Nn * DHh;
  const unsigned short* vbase = vt + (size_t)bh * DHh * Nn;

  // Q fragments (q pre-scaled by 8*log2e); lane layout = MFMA B-operand
  bf16x8 aq[2][2];
  #pragma unroll
  for (int i2 = 0; i2 < 2; i2++)
    #pragma unroll
    for (int kk = 0; kk < 2; kk++)
      aq[i2][kk] = *(const bf16x8*)(qbase + (size_t)(m0 + i2 * 16 + l16) * DHh + kk * 32 + quad * 8);

  f32x4 accOT[4][2] = {};       // [dt][i2]: O^T, row=d=quad*4+r, col=m=l16
  float den[2] = {};            // per-lane partial (quad-partial), m = i2*16+l16

  int tl = t & 255;                      // thread-in-halfgroup
  int srow = tl >> 3;                    // 0..31
  int gch = (tl & 7) ^ (srow & 7);       // swizzled chunk
  int nh = qb + 1;                       // tiles per half
  int kt0 = half * nh;

  // stage this half's tile kt_ into buffer b_ (4 GLDS16 per thread)
  auto stageT = [&](int kt_, int b_) {
    int jj = (kt0 + kt_) * 64;
    unsigned short* K_ = (unsigned short*)((char*)smemf + half * 32768 + b_ * 16384);
    unsigned short* V_ = K_ + 4096;
    GLDS16(kbase + (size_t)(jj + srow)      * DHh + gch * 8, K_ + (size_t)tl * 8);
    GLDS16(kbase + (size_t)(jj + srow + 32) * DHh + gch * 8, K_ + (size_t)(tl + 256) * 8);
    GLDS16(vbase + (size_t)srow        * Nn + jj + gch * 8, V_ + (size_t)tl * 8);
    GLDS16(vbase + (size_t)(srow + 32) * Nn + jj + gch * 8, V_ + (size_t)(tl + 256) * 8);
  };

  // prologue: two tiles in flight
  stageT(0, 0);
  if (nh > 1) stageT(1, 1);

  for (int kt = 0; kt < nh; kt++) {
    if (kt < nh - 1) asm volatile("s_waitcnt vmcnt(4)" ::: "memory");
    else             asm volatile("s_waitcnt vmcnt(0)" ::: "memory");
    __builtin_amdgcn_s_barrier();
    __builtin_amdgcn_sched_barrier(0);
    int j0 = (kt0 + kt) * 64;
    unsigned short* myK = (unsigned short*)((char*)smemf + half * 32768 + (kt & 1) * 16384);
    unsigned short* myV = myK + 4096;

    if (j0 <= m0 + 31) {                 // not fully masked (wave-uniform)
      // S^T = K·Q^T : sc[jt][i2], row=j_local=quad*4+r, col=m_local=l16
      f32x4 sc[4][2] = {};
      #pragma unroll
      for (int kk = 0; kk < 2; kk++) {
        int slot = (kk * 4 + quad) ^ (l16 & 7);
        #pragma unroll
        for (int jt = 0; jt < 4; jt++) {
          bf16x8 ak = *(const bf16x8*)(myK + (size_t)(jt * 16 + l16) * 64 + slot * 8);
          #pragma unroll
          for (int i2 = 0; i2 < 2; i2++)
            sc[jt][i2] = __builtin_amdgcn_mfma_f32_16x16x32_bf16(ak, aq[i2][kk], sc[jt][i2], 0, 0, 0);
        }
      }

      // p = 2^(sc - 8*log2e) in-register (v_exp_f32 directly, no mul)
      bool fullTile = (j0 + 63) <= m0;   // wave-uniform
      s16x4 pf[4][2];
      #pragma unroll
      for (int jt = 0; jt < 4; jt++) {
        #pragma unroll
        for (int i2 = 0; i2 < 2; i2++) {
          int m = m0 + i2 * 16 + l16;
          #pragma unroll
          for (int r = 0; r < 4; r++) {
            int j = j0 + jt * 16 + quad * 4 + r;
            float e = sc[jt][i2][r] - 11.5415603f;
            float p;
            asm("v_exp_f32 %0, %1" : "=v"(p) : "v"(e));
            if (!fullTile && j > m) p = 0.0f;
            den[i2] += p;
            pf[jt][i2][r] = (short)f2bf_fast(p);
          }
        }
      }

      // O^T += V^T · P^T  (A = V^T frag from LDS, 4 bf16/lane: [d=l16][j=quad*4+i])
      #pragma unroll
      for (int jt = 0; jt < 4; jt++) {
        #pragma unroll
        for (int dt = 0; dt < 4; dt++) {
          int row = dt * 16 + l16;
          int ch = (jt * 2 + (quad >> 1)) ^ (l16 & 7);
          s16x4 av = *(const s16x4*)(myV + (size_t)row * 64 + ch * 8 + (quad & 1) * 4);
          #pragma unroll
          for (int i2 = 0; i2 < 2; i2++)
            accOT[dt][i2] = __builtin_amdgcn_mfma_f32_16x16x16bf16_1k(av, pf[jt][i2], accOT[dt][i2], 0, 0, 0);
        }
      }
    }

    __builtin_amdgcn_sched_barrier(0);
    __builtin_amdgcn_s_barrier();
    __builtin_amdgcn_sched_barrier(0);
    if (kt + 2 < nh) stageT(kt + 2, kt & 1);
  }

  // intra-wave den reduction across quads (j-direction lives on lane>>4)
  #pragma unroll
  for (int i2 = 0; i2 < 2; i2++) {
    float d = den[i2];
    d += __shfl_xor(d, 16); d += __shfl_xor(d, 32);
    den[i2] = d;
  }

  // merge halves through LDS (reuse tile buffers; all loop reads done)
  __syncthreads();
  float* scr = smemf + strip * 2176;     // 2048 acc + 128 den per strip
  if (half == 1) {
    #pragma unroll
    for (int dt = 0; dt < 4; dt++)
      #pragma unroll
      for (int i2 = 0; i2 < 2; i2++)
        *(f32x4*)(scr + ((size_t)(dt * 2 + i2) * 64 + lane) * 4) = accOT[dt][i2];
    scr[2048 + lane] = den[0];
    scr[2048 + 64 + lane] = den[1];
  }
  __syncthreads();
  if (half == 0) {
    float dinv[2];
    dinv[0] = 1.0f / (den[0] + scr[2048 + lane]);
    dinv[1] = 1.0f / (den[1] + scr[2048 + 64 + lane]);
    int bi = bh >> 4, h = bh & 15;
    #pragma unroll
    for (int i2 = 0; i2 < 2; i2++) {
      #pragma unroll
      for (int dt = 0; dt < 4; dt++) {
        f32x4 o = accOT[dt][i2] + *(const f32x4*)(scr + ((size_t)(dt * 2 + i2) * 64 + lane) * 4);
        ushort4 o4;
        o4.x = f2bf(o[0] * dinv[i2]);
        o4.y = f2bf(o[1] * dinv[i2]);
        o4.z = f2bf(o[2] * dinv[i2]);
        o4.w = f2bf(o[3] * dinv[i2]);
        int ns = m0 + i2 * 16 + l16;
        int d0 = dt * 16 + quad * 4;
        *(ushort4*)(o_flat + ((size_t)(bi * Nn + ns)) * DIMM + h * DHh + d0) = o4;
      }
    }
  }
}

// ---------------------------------------------------------------------------
extern "C" void kernel_launch(void* const* d_in, const int* in_sizes, int n_in,
                              void* d_out, int out_size, void* d_ws, size_t ws_size,
                              hipStream_t stream) {
  const float* x        = (const float*)d_in[0];
  const float* g        = (const float*)d_in[1];
  const float* b        = (const float*)d_in[2];
  const float* c_attn_w = (const float*)d_in[3];
  const float* c_attn_b = (const float*)d_in[4];
  const float* c_proj_w = (const float*)d_in[5];
  const float* c_proj_b = (const float*)d_in[6];
  const float* to_out_w = (const float*)d_in[7];
  float* out = (float*)d_out;

  char* p = (char*)d_ws;
  unsigned short* y     = (unsigned short*)(p + ((size_t)0  << 20)); // 8 MB (also o_flat)
  unsigned short* qbuf  = (unsigned short*)(p + ((size_t)8  << 20)); // 8 MB
  unsigned short* kbuf  = (unsigned short*)(p + ((size_t)16 << 20)); // 8 MB
  unsigned short* vtb   = (unsigned short*)(p + ((size_t)24 << 20)); // 8 MB (V^T, written by qkv epilogue)
  unsigned short* wpbf  = (unsigned short*)(p + ((size_t)32 << 20)); // 2 MB
  unsigned short* wout  = (unsigned short*)(p + ((size_t)34 << 20)); // 2 MB
  unsigned short* wqkv  = (unsigned short*)(p + ((size_t)40 << 20)); // 6 MB
  unsigned short* wcomb = (unsigned short*)(p + ((size_t)46 << 20)); // 2 MB
  float*          bc    = (float*)        (p + ((size_t)48 << 20)); // 4 KB

  // 1. fused prep: LayerNorm -> y, transpose c_attn_w, convert wp/wout, bias
  prep_kernel<<<9472, 256, 0, stream>>>(x, g, b, c_attn_w, c_proj_w, to_out_w,
                                        c_proj_b, y, wqkv, wpbf, wout, bc);
  // 2. qkv GEMM (+fused l2norm, +fused V-transpose) with wcomb GEMM riding
  gemm_qkv_wcomb<<<dim3(26, MROWS / 128), 512, 0, stream>>>(
      y, wqkv, c_attn_b, qbuf, kbuf, vtb, wout, wpbf, wcomb);
  // 3. attention -> o_flat (reuses y)
  attn_kernel<<<512, 512, 0, stream>>>(qbuf, kbuf, vtb, y);
  // 4. fused (c_proj ∘ to_out): out = o_flat @ wcomb^T + bc  (fp32)
  gemm_final<<<dim3(DIMM / 128, MROWS / 128), 512, 0, stream>>>(y, wcomb, bc, out);
}